// Round 2
// baseline (233.042 us; speedup 1.0000x reference)
//
#include <hip/hip_runtime.h>

typedef _Float16 f16;
typedef _Float16 f16x4 __attribute__((ext_vector_type(4)));
typedef _Float16 f16x8 __attribute__((ext_vector_type(8)));
typedef float f32x4 __attribute__((ext_vector_type(4)));

static __device__ __forceinline__ f32x4 mfma_k32(f16x8 a, f16x8 b, f32x4 c) {
  return __builtin_amdgcn_mfma_f32_16x16x32_f16(a, b, c, 0, 0, 0);
}
static __device__ __forceinline__ f32x4 mfma_k16(f16x4 a, f16x4 b, f32x4 c) {
  return __builtin_amdgcn_mfma_f32_16x16x16f16(a, b, c, 0, 0, 0);
}

#define BN 2048    // sequence length
#define CC 512     // channels
#define NHD 64     // head dim
#define MROWS 8192 // B*N
#define SLAB ((size_t)32 * BN * NHD)  // one of Q/K/V: 4,194,304 f16

// ---------------------------------------------------------------------------
// QKV GEMM: C[m][d] = sum_k X[m][k] * Wqkv[d][k]
// M=8192, D=1536, K=512.
// Epilogue: Q (scaled 0.125) and K -> (b,h,n,hd); V -> TRANSPOSED (b,h,hd,n).
// ---------------------------------------------------------------------------
__global__ __launch_bounds__(256)
void qkv_gemm(const float* __restrict__ X, const float* __restrict__ W,
              f16* __restrict__ qkv) {
  __shared__ __align__(16) f16 As[128][40];
  __shared__ __align__(16) f16 Bs[128][40];
  const int t = threadIdx.x;
  const int lane = t & 63, wave = t >> 6;
  const int wr = wave >> 1, wc = wave & 1;
  const int mt = blockIdx.x / 12, nt = blockIdx.x % 12;
  const int m0 = mt * 128, n0 = nt * 128;
  const int grp = lane >> 4, lid = lane & 15;

  const f32x4 zf = {0.f, 0.f, 0.f, 0.f};
  f32x4 acc[4][4];
#pragma unroll
  for (int i = 0; i < 4; i++)
#pragma unroll
    for (int j = 0; j < 4; j++) acc[i][j] = zf;

  const int r = t >> 1, hh = (t & 1) * 16;
  for (int k0 = 0; k0 < CC; k0 += 32) {
    const float* sa = X + (size_t)(m0 + r) * CC + k0 + hh;
    const float* sb = W + (size_t)(n0 + r) * CC + k0 + hh;
#pragma unroll
    for (int j = 0; j < 4; j++) {
      float4 va = *(const float4*)(sa + 4 * j);
      float4 vb = *(const float4*)(sb + 4 * j);
      f16x4 fa = {(f16)va.x, (f16)va.y, (f16)va.z, (f16)va.w};
      f16x4 fb = {(f16)vb.x, (f16)vb.y, (f16)vb.z, (f16)vb.w};
      *(f16x4*)&As[r][hh + 4 * j] = fa;
      *(f16x4*)&Bs[r][hh + 4 * j] = fb;
    }
    __syncthreads();
    f16x8 af[4], bf[4];
#pragma unroll
    for (int mi = 0; mi < 4; mi++)
      af[mi] = *(const f16x8*)&As[wr * 64 + mi * 16 + lid][grp * 8];
#pragma unroll
    for (int ni = 0; ni < 4; ni++)
      bf[ni] = *(const f16x8*)&Bs[wc * 64 + ni * 16 + lid][grp * 8];
#pragma unroll
    for (int mi = 0; mi < 4; mi++)
#pragma unroll
      for (int ni = 0; ni < 4; ni++)
        acc[mi][ni] = mfma_k32(af[mi], bf[ni], acc[mi][ni]);
    __syncthreads();
  }
  // epilogue
#pragma unroll
  for (int ni = 0; ni < 4; ni++) {
    int d = n0 + wc * 64 + ni * 16 + lid;
    int s = d >> 9;
    int h = (d & 511) >> 6;
    int hd = d & 63;
    if (s == 2) {
      // V transposed: vT[((b*8+h)*64+hd)*2048 + n], vectorized 4-row store
#pragma unroll
      for (int mi = 0; mi < 4; mi++) {
        int row0 = m0 + wr * 64 + mi * 16 + grp * 4;
        int b = row0 >> 11, n = row0 & 2047;
        f16x4 pk = {(f16)acc[mi][ni][0], (f16)acc[mi][ni][1],
                    (f16)acc[mi][ni][2], (f16)acc[mi][ni][3]};
        *(f16x4*)&qkv[2 * SLAB + ((size_t)((b * 8 + h) * 64 + hd)) * BN + n] = pk;
      }
    } else {
      float scale = (s == 0) ? 0.125f : 1.0f;
#pragma unroll
      for (int mi = 0; mi < 4; mi++) {
#pragma unroll
        for (int i = 0; i < 4; i++) {
          int row = m0 + wr * 64 + mi * 16 + grp * 4 + i;
          int b = row >> 11, n = row & 2047;
          qkv[(size_t)s * SLAB + (((size_t)(b * 8 + h) * BN + n)) * NHD + hd] =
              (f16)(acc[mi][ni][i] * scale);
        }
      }
    }
  }
}

// ---------------------------------------------------------------------------
// Flash attention, LDS-free, barrier-free.
// Block = 128 q-rows of one (b,h); 4 waves x 32 q-rows (2 q-tiles of 16).
// Swapped QK^T (mfma(K,Q)): lane (qv,grp) holds S[q=qv][key=kt*16+grp*4+i]
// -> softmax P feeds PV (16x16x16 B-operand) directly from registers.
// PV: O^T[dt] += V^T_frag . P ; V^T read straight from global (L2-resident).
// ---------------------------------------------------------------------------
__global__ __launch_bounds__(256)
void attn(const f16* __restrict__ qkv, f16* __restrict__ O) {
  const int bh = blockIdx.x >> 4;  // b*8+h
  const int qb = blockIdx.x & 15;  // 16 q-blocks of 128 rows
  const f16* Q = qkv + (size_t)bh * BN * NHD;
  const f16* K = qkv + SLAB + (size_t)bh * BN * NHD;
  const f16* VT = qkv + 2 * SLAB + (size_t)bh * NHD * BN;  // (hd, n)
  const int t = threadIdx.x, lane = t & 63, wave = t >> 6;
  const int grp = lane >> 4, qv = lane & 15;
  const int qrow0 = qb * 128 + wave * 32 + qv;  // q-tile 0; tile 1 = +16

  f16x8 qf[2][2];
#pragma unroll
  for (int qt = 0; qt < 2; qt++) {
    const f16* qr = Q + (size_t)(qrow0 + qt * 16) * NHD;
    qf[qt][0] = *(const f16x8*)(qr + grp * 8);
    qf[qt][1] = *(const f16x8*)(qr + 32 + grp * 8);
  }

  const f32x4 zf = {0.f, 0.f, 0.f, 0.f};
  f32x4 acc[2][4];
#pragma unroll
  for (int qt = 0; qt < 2; qt++)
#pragma unroll
    for (int dt = 0; dt < 4; dt++) acc[qt][dt] = zf;
  float m[2] = {-1e30f, -1e30f}, l[2] = {0.f, 0.f};

  for (int k0 = 0; k0 < BN; k0 += 32) {
    // K fragments (shared across both q-tiles)
    f16x8 kf[2][2];
#pragma unroll
    for (int kt = 0; kt < 2; kt++) {
      const f16* kr = K + (size_t)(k0 + kt * 16 + qv) * NHD;
      kf[kt][0] = *(const f16x8*)(kr + grp * 8);
      kf[kt][1] = *(const f16x8*)(kr + 32 + grp * 8);
    }
    // V^T fragments: A-operand of 16x16x16, lane(qv,grp):
    // V^T[d=dt*16+qv][k0+kt*16+grp*4 .. +3]
    f16x4 vf[4][2];
#pragma unroll
    for (int dt = 0; dt < 4; dt++)
#pragma unroll
      for (int kt = 0; kt < 2; kt++)
        vf[dt][kt] = *(const f16x4*)(VT + (size_t)(dt * 16 + qv) * BN + k0 +
                                     kt * 16 + grp * 4);

#pragma unroll
    for (int qt = 0; qt < 2; qt++) {
      f32x4 st[2];
#pragma unroll
      for (int kt = 0; kt < 2; kt++)
        st[kt] = mfma_k32(kf[kt][1], qf[qt][1],
                          mfma_k32(kf[kt][0], qf[qt][0], zf));
      // online softmax for q = qv (replicated across the 4 groups)
      float mt = st[0][0];
#pragma unroll
      for (int kt = 0; kt < 2; kt++)
#pragma unroll
        for (int i = 0; i < 4; i++) mt = fmaxf(mt, st[kt][i]);
      mt = fmaxf(mt, __shfl_xor(mt, 16));
      mt = fmaxf(mt, __shfl_xor(mt, 32));
      float newm = fmaxf(m[qt], mt);
      float fsc = __expf(m[qt] - newm);
      f16x4 pb[2];
      float ps = 0.f;
#pragma unroll
      for (int kt = 0; kt < 2; kt++)
#pragma unroll
        for (int i = 0; i < 4; i++) {
          float e = __expf(st[kt][i] - newm);
          ps += e;
          pb[kt][i] = (f16)e;
        }
      ps += __shfl_xor(ps, 16);
      ps += __shfl_xor(ps, 32);
      l[qt] = l[qt] * fsc + ps;
      m[qt] = newm;
#pragma unroll
      for (int dt = 0; dt < 4; dt++) acc[qt][dt] *= fsc;
      // PV: 16x16x16, A = V^T frag, B = P (direct from softmax layout)
#pragma unroll
      for (int dt = 0; dt < 4; dt++)
#pragma unroll
        for (int kt = 0; kt < 2; kt++)
          acc[qt][dt] = mfma_k16(vf[dt][kt], pb[kt], acc[qt][dt]);
    }
  }
  // epilogue -> O (B,N,C) f16, vectorized 8B stores
  const int b = bh >> 3, h = bh & 7;
#pragma unroll
  for (int qt = 0; qt < 2; qt++) {
    float inv = 1.0f / l[qt];
    int q_row = qrow0 + qt * 16;
#pragma unroll
    for (int dt = 0; dt < 4; dt++) {
      f16x4 o = {(f16)(acc[qt][dt][0] * inv), (f16)(acc[qt][dt][1] * inv),
                 (f16)(acc[qt][dt][2] * inv), (f16)(acc[qt][dt][3] * inv)};
      *(f16x4*)&O[((size_t)(b * BN + q_row)) * CC + h * NHD + dt * 16 + grp * 4] = o;
    }
  }
}

// ---------------------------------------------------------------------------
// Output projection: out[m][d] = sum_c A[m][c] * Wproj[d][c] + bias[d]
// ---------------------------------------------------------------------------
__global__ __launch_bounds__(256)
void proj_gemm(const f16* __restrict__ A, const float* __restrict__ W,
               const float* __restrict__ bias, float* __restrict__ out) {
  __shared__ __align__(16) f16 As[128][40];
  __shared__ __align__(16) f16 Bs[128][40];
  const int t = threadIdx.x;
  const int lane = t & 63, wave = t >> 6;
  const int wr = wave >> 1, wc = wave & 1;
  const int mt = blockIdx.x >> 2, nt = blockIdx.x & 3;
  const int m0 = mt * 128, n0 = nt * 128;
  const int grp = lane >> 4, lid = lane & 15;

  const f32x4 zf = {0.f, 0.f, 0.f, 0.f};
  f32x4 acc[4][4];
#pragma unroll
  for (int i = 0; i < 4; i++)
#pragma unroll
    for (int j = 0; j < 4; j++) acc[i][j] = zf;

  const int r = t >> 1, hh = (t & 1) * 16;
  for (int k0 = 0; k0 < CC; k0 += 32) {
    const f16* sa = A + (size_t)(m0 + r) * CC + k0 + hh;
    f16x8 a0 = *(const f16x8*)sa;
    f16x8 a1 = *(const f16x8*)(sa + 8);
    *(f16x8*)&As[r][hh] = a0;
    *(f16x8*)&As[r][hh + 8] = a1;
    const float* sb = W + (size_t)(n0 + r) * CC + k0 + hh;
#pragma unroll
    for (int j = 0; j < 4; j++) {
      float4 vb = *(const float4*)(sb + 4 * j);
      f16x4 fb = {(f16)vb.x, (f16)vb.y, (f16)vb.z, (f16)vb.w};
      *(f16x4*)&Bs[r][hh + 4 * j] = fb;
    }
    __syncthreads();
    f16x8 af[4], bf[4];
#pragma unroll
    for (int mi = 0; mi < 4; mi++)
      af[mi] = *(const f16x8*)&As[wr * 64 + mi * 16 + lid][grp * 8];
#pragma unroll
    for (int ni = 0; ni < 4; ni++)
      bf[ni] = *(const f16x8*)&Bs[wc * 64 + ni * 16 + lid][grp * 8];
#pragma unroll
    for (int mi = 0; mi < 4; mi++)
#pragma unroll
      for (int ni = 0; ni < 4; ni++)
        acc[mi][ni] = mfma_k32(af[mi], bf[ni], acc[mi][ni]);
    __syncthreads();
  }
#pragma unroll
  for (int mi = 0; mi < 4; mi++) {
#pragma unroll
    for (int ni = 0; ni < 4; ni++) {
      int d = n0 + wc * 64 + ni * 16 + lid;
      float bv = bias[d];
#pragma unroll
      for (int i = 0; i < 4; i++) {
        int row = m0 + wr * 64 + mi * 16 + grp * 4 + i;
        out[(size_t)row * CC + d] = acc[mi][ni][i] + bv;
      }
    }
  }
}

extern "C" void kernel_launch(void* const* d_in, const int* in_sizes, int n_in,
                              void* d_out, int out_size, void* d_ws, size_t ws_size,
                              hipStream_t stream) {
  const float* x = (const float*)d_in[0];
  const float* w_qkv = (const float*)d_in[1];
  const float* w_proj = (const float*)d_in[2];
  const float* b_proj = (const float*)d_in[3];
  float* out = (float*)d_out;

  f16* qkv = (f16*)d_ws;                     // 3 slabs = 25.2 MB
  f16* Obuf = qkv + 3 * SLAB;                // 8.4 MB

  qkv_gemm<<<dim3(64 * 12), dim3(256), 0, stream>>>(x, w_qkv, qkv);
  attn<<<dim3(32 * 16), dim3(256), 0, stream>>>(qkv, Obuf);
  proj_gemm<<<dim3(64 * 4), dim3(256), 0, stream>>>(Obuf, w_proj, b_proj, out);
}